// Round 5
// baseline (364.416 us; speedup 1.0000x reference)
//
#include <hip/hip_runtime.h>

typedef unsigned short u16;
typedef __bf16 bf16x8 __attribute__((ext_vector_type(8)));
typedef float f32x16 __attribute__((ext_vector_type(16)));

__device__ __forceinline__ u16 f2bf(float f) {
    unsigned u = __builtin_bit_cast(unsigned, f);
    u += 0x7fffu + ((u >> 16) & 1u);
    return (u16)(u >> 16);
}

#define GLDS16(g, l) __builtin_amdgcn_global_load_lds( \
    (const __attribute__((address_space(1))) void*)(g), \
    (__attribute__((address_space(3))) void*)(l), 16, 0, 0)

// explicit waits with memory clobber so the compiler cannot move LDS ops across
#define WAIT_VM0()   asm volatile("s_waitcnt vmcnt(0)" ::: "memory")
#define WAIT_ALL0()  asm volatile("s_waitcnt vmcnt(0) lgkmcnt(0)" ::: "memory")

#define QK_SCALE 0.044194173824159216f

// ---------------------------------------------------------------------------
// Weight conversion: fp32 -> bf16 (Wq|Wk|Wv stacked row-major, Wp), biases.
// Wq and bq pre-scaled by C^-1/2 so QK^T comes out pre-scaled.
// ---------------------------------------------------------------------------
__global__ __launch_bounds__(256) void convert_kernel(
    const float* __restrict__ Wq, const float* __restrict__ Wk,
    const float* __restrict__ Wv, const float* __restrict__ Wp,
    const float* __restrict__ bq, const float* __restrict__ bk,
    const float* __restrict__ bv,
    u16* __restrict__ Wqkv, u16* __restrict__ Wpb, float* __restrict__ bqkv)
{
    int idx = blockIdx.x * 256 + threadIdx.x;  // 4096 * 256 = 1048576
    if (idx < 786432) {
        int which = idx >> 18;
        int off   = idx & 262143;
        if (which == 0)
            Wqkv[idx] = f2bf(Wq[off] * QK_SCALE);
        else
            Wqkv[idx] = f2bf(((which == 1) ? Wk : Wv)[off]);
    } else {
        int off = idx - 786432;
        Wpb[off] = f2bf(Wp[off]);
    }
    if (idx < 1536) {
        float bvv = (idx < 512) ? bq[idx] * QK_SCALE
                  : (idx < 1024) ? bk[idx & 511] : bv[idx & 511];
        bqkv[idx] = bvv;
    }
}

// ---------------------------------------------------------------------------
// GroupNorm: x [B,C,T] fp32 -> h_t [B,T,C] bf16.  One block per (b, group).
// ---------------------------------------------------------------------------
__global__ __launch_bounds__(256) void gn_kernel(
    const float* __restrict__ x, const float* __restrict__ gamma,
    const float* __restrict__ beta, u16* __restrict__ ht)
{
    const int g = blockIdx.x, b = blockIdx.y, tid = threadIdx.x;
    const float* xg = x + ((size_t)b * 512 + (size_t)g * 16) * 1024;

    float s = 0.f, s2 = 0.f;
    const float4* x4 = (const float4*)xg;
    #pragma unroll 4
    for (int i = tid; i < 4096; i += 256) {
        float4 v = x4[i];
        s  += v.x + v.y + v.z + v.w;
        s2 += v.x * v.x + v.y * v.y + v.z * v.z + v.w * v.w;
    }
    #pragma unroll
    for (int off = 32; off; off >>= 1) {
        s  += __shfl_down(s, off);
        s2 += __shfl_down(s2, off);
    }
    __shared__ float rs[4], rs2[4];
    __shared__ float stat[2];
    const int w = tid >> 6;
    if ((tid & 63) == 0) { rs[w] = s; rs2[w] = s2; }
    __syncthreads();
    if (tid == 0) {
        float S  = rs[0] + rs[1] + rs[2] + rs[3];
        float S2 = rs2[0] + rs2[1] + rs2[2] + rs2[3];
        float mean = S * (1.f / 16384.f);
        float var  = S2 * (1.f / 16384.f) - mean * mean;
        stat[0] = mean;
        stat[1] = rsqrtf(var + 1e-5f);
    }
    __syncthreads();
    const float mean = stat[0], rstd = stat[1];

    float ga[16], be[16];
    #pragma unroll
    for (int ci = 0; ci < 16; ci++) {
        ga[ci] = gamma[g * 16 + ci];
        be[ci] = beta[g * 16 + ci];
    }
    for (int t = tid; t < 1024; t += 256) {
        u16 yv[16];
        #pragma unroll
        for (int ci = 0; ci < 16; ci++) {
            float v = xg[ci * 1024 + t];
            yv[ci] = f2bf((v - mean) * rstd * ga[ci] + be[ci]);
        }
        uint4* dst = (uint4*)(ht + ((size_t)b * 1024 + t) * 512 + g * 16);
        dst[0] = ((const uint4*)yv)[0];
        dst[1] = ((const uint4*)yv)[1];
    }
}

// ---------------------------------------------------------------------------
// NT GEMM (R3 structure): C[m][n] = sum_k A[m][k]*B[n][k], 128x128 tile,
// BK=64, 4 waves of 2x2 32x32x16 frags, dual-LDS, XOR chunk swizzle.
// MODE 0: qkv -> q,k bf16 row-major [B,T,C]/[B,S,C]; v bf16 [B,C,S]; +bias
// MODE 3: proj -> fp32 d_out[B,C,T] = acc + bias[n] + x
// ---------------------------------------------------------------------------
template <int MODE>
__global__ __launch_bounds__(256) void gemm_nt(
    const u16* __restrict__ A, const u16* __restrict__ B,
    size_t strideA, size_t strideB, int lda, int ldb, int K,
    u16* __restrict__ o0, u16* __restrict__ o1, u16* __restrict__ o2,
    float* __restrict__ fo, const float* __restrict__ bias,
    const float* __restrict__ xres)
{
    __shared__ u16 As[128 * 64];
    __shared__ u16 Bs[128 * 64];

    const int tid   = threadIdx.x;
    const int lane  = tid & 63;
    const int wave  = tid >> 6;
    const int wm    = (wave >> 1) * 64;
    const int wn    = (wave & 1) * 64;
    const int l31   = lane & 31;
    const int khalf = lane >> 5;
    const int b     = blockIdx.z;

    const u16* Ab = A + (size_t)b * strideA + (size_t)blockIdx.y * 128 * lda;
    const u16* Bb = B + (size_t)b * strideB + (size_t)blockIdx.x * 128 * ldb;

    const int srow = lane >> 3;
    const int sc   = lane & 7;
    const int scg  = sc ^ srow;

    f32x16 acc[2][2] = {};

    for (int k0 = 0; k0 < K; k0 += 64) {
        __syncthreads();
        #pragma unroll
        for (int s = 0; s < 4; s++) {
            const int r = wave * 32 + s * 8 + srow;
            GLDS16(Ab + (size_t)r * lda + k0 + scg * 8, As + r * 64 + sc * 8);
            GLDS16(Bb + (size_t)r * ldb + k0 + scg * 8, Bs + r * 64 + sc * 8);
        }
        __syncthreads();

        #pragma unroll
        for (int ks = 0; ks < 4; ks++) {
            const int cidx = ks * 2 + khalf;
            bf16x8 af[2], bfr[2];
            #pragma unroll
            for (int i = 0; i < 2; i++) {
                const int r = wm + i * 32 + l31;
                af[i] = *(const bf16x8*)(As + r * 64 + ((cidx ^ (r & 7)) * 8));
            }
            #pragma unroll
            for (int j = 0; j < 2; j++) {
                const int r = wn + j * 32 + l31;
                bfr[j] = *(const bf16x8*)(Bs + r * 64 + ((cidx ^ (r & 7)) * 8));
            }
            #pragma unroll
            for (int i = 0; i < 2; i++)
                #pragma unroll
                for (int j = 0; j < 2; j++)
                    acc[i][j] = __builtin_amdgcn_mfma_f32_32x32x16_bf16(
                        af[i], bfr[j], acc[i][j], 0, 0, 0);
        }
    }

    const int m_base = blockIdx.y * 128 + wm + 4 * khalf;
    const int n_base = blockIdx.x * 128 + wn + l31;

    #pragma unroll
    for (int i = 0; i < 2; i++) {
        #pragma unroll
        for (int j = 0; j < 2; j++) {
            const int n = n_base + j * 32;
            float bv = 0.f;
            if (MODE == 0 || MODE == 3) bv = bias[n];
            #pragma unroll
            for (int g = 0; g < 4; g++) {
                const int m = m_base + i * 32 + 8 * g;
                const float a0 = acc[i][j][4 * g]     + bv;
                const float a1 = acc[i][j][4 * g + 1] + bv;
                const float a2 = acc[i][j][4 * g + 2] + bv;
                const float a3 = acc[i][j][4 * g + 3] + bv;
                if (MODE == 0) {
                    if (n < 1024) {          // q or k: row-major [.,C], scalar
                        u16* dst = (n < 512) ? o0 : o1;
                        const int nn = n & 511;
                        dst[((size_t)b * 1024 + m) * 512 + nn]     = f2bf(a0);
                        dst[((size_t)b * 1024 + m + 1) * 512 + nn] = f2bf(a1);
                        dst[((size_t)b * 1024 + m + 2) * 512 + nn] = f2bf(a2);
                        dst[((size_t)b * 1024 + m + 3) * 512 + nn] = f2bf(a3);
                    } else {                 // v: [B,C,S], ushort4
                        ushort4 hv = {f2bf(a0), f2bf(a1), f2bf(a2), f2bf(a3)};
                        *(ushort4*)(o2 + ((size_t)b * 512 + (n - 1024)) * 1024 + m) = hv;
                    }
                } else {                     // proj + bias + residual, [B,C,T]
                    const size_t off = ((size_t)b * 512 + n) * 1024 + m;
                    const float4 xv = *(const float4*)(xres + off);
                    float4 ov = {a0 + xv.x, a1 + xv.y, a2 + xv.z, a3 + xv.w};
                    *(float4*)(fo + off) = ov;
                }
            }
        }
    }
}

// ---------------------------------------------------------------------------
// Fused flash attention: per block = 64 q-rows of one batch.
// q [B,T,C], k [B,S,C], v [B,C,S] bf16 -> o (=h2) [B,T,C] bf16.
// s-loop: 4 iters of 256 s.  Phase1: S'[256s][64t] = k.q^T (wave = 64 s rows,
// wave-private LDS quarter, barrier-free k/q staging).  Online softmax with
// cross-wave LDS reduction.  Phase2: O[64t][512c] += P.v^T (wave = 128 c).
// ---------------------------------------------------------------------------
__global__ __launch_bounds__(256, 2) void attn_fused(
    const u16* __restrict__ q, const u16* __restrict__ k,
    const u16* __restrict__ v, u16* __restrict__ o)
{
    __shared__ u16 shA[16384];   // 32KB: k-chunks / stats / v-chunks (wave quarters)
    __shared__ u16 shB[16384];   // 32KB: per-wave q copies, then P [64][256]
    float* statf = (float*)shA;  // pmax @0, psum @256, alpha/linv @512 (wave-0 quarter)

    const int tid  = threadIdx.x;
    const int lane = tid & 63, w = tid >> 6;
    const int l31  = lane & 31, kh = lane >> 5;
    const int b = blockIdx.y, t0 = blockIdx.x * 64;

    const u16* qb = q + (size_t)b * 524288 + (size_t)t0 * 512;
    const u16* kb = k + (size_t)b * 524288;
    const u16* vb = v + (size_t)b * 524288;

    const int srow8  = lane >> 3, sc8 = lane & 7;
    const int srow16 = lane >> 2, sc4 = lane & 3;

    f32x16 oacc[2][4] = {};
    float m_run[2] = {-3e38f, -3e38f};
    float l_run[2] = {0.f, 0.f};

    for (int s0 = 0; s0 < 1024; s0 += 256) {
        // ---------------- phase 1: S' = k . q^T ----------------
        f32x16 sacc[2][2] = {};
        for (int k0 = 0; k0 < 512; k0 += 64) {
            WAIT_ALL0();   // own prior LDS reads done before DMA overwrite
            #pragma unroll
            for (int g = 0; g < 8; g++) {      // k rows: wave-private 64 s
                const int r = w * 64 + g * 8 + srow8;
                GLDS16(kb + (size_t)(s0 + r) * 512 + k0 + ((sc8 ^ (r & 7)) * 8),
                       shA + r * 64 + sc8 * 8);
            }
            #pragma unroll
            for (int g = 0; g < 8; g++) {      // private q copy (64 t rows)
                const int r = g * 8 + srow8;
                GLDS16(qb + (size_t)r * 512 + k0 + ((sc8 ^ (r & 7)) * 8),
                       shB + w * 4096 + r * 64 + sc8 * 8);
            }
            WAIT_VM0();
            #pragma unroll
            for (int ks = 0; ks < 4; ks++) {
                const int cidx = ks * 2 + kh;
                bf16x8 af[2], bq2[2];
                #pragma unroll
                for (int i = 0; i < 2; i++) {
                    const int r = w * 64 + i * 32 + l31;
                    af[i] = *(const bf16x8*)(shA + r * 64 + ((cidx ^ (r & 7)) * 8));
                }
                #pragma unroll
                for (int j = 0; j < 2; j++) {
                    const int r = j * 32 + l31;
                    bq2[j] = *(const bf16x8*)(shB + w * 4096 + r * 64 +
                                              ((cidx ^ (r & 7)) * 8));
                }
                #pragma unroll
                for (int i = 0; i < 2; i++)
                    #pragma unroll
                    for (int j = 0; j < 2; j++)
                        sacc[i][j] = __builtin_amdgcn_mfma_f32_32x32x16_bf16(
                            af[i], bq2[j], sacc[i][j], 0, 0, 0);
            }
        }
        __syncthreads();                                   // B0: phase1 done
        // ---------------- online softmax ----------------
        float tm[2], al[2];
        #pragma unroll
        for (int j = 0; j < 2; j++) {
            float m = sacc[0][j][0];
            #pragma unroll
            for (int r = 1; r < 16; r++) m = fmaxf(m, sacc[0][j][r]);
            #pragma unroll
            for (int r = 0; r < 16; r++) m = fmaxf(m, sacc[1][j][r]);
            m = fmaxf(m, __shfl_xor(m, 32));
            tm[j] = m;
        }
        if (kh == 0) {
            statf[w * 64 + l31]      = tm[0];
            statf[w * 64 + 32 + l31] = tm[1];
        }
        __syncthreads();                                   // B1: pmax visible
        #pragma unroll
        for (int j = 0; j < 2; j++) {
            const int tj = j * 32 + l31;
            float M = statf[tj];
            #pragma unroll
            for (int wi = 1; wi < 4; wi++) M = fmaxf(M, statf[wi * 64 + tj]);
            const float m_new = fmaxf(m_run[j], M);
            al[j] = __expf(m_run[j] - m_new);
            m_run[j] = m_new;
            float ls = 0.f;
            #pragma unroll
            for (int i = 0; i < 2; i++)
                #pragma unroll
                for (int r = 0; r < 16; r++) {
                    float p = __expf(sacc[i][j][r] - m_new);
                    sacc[i][j][r] = p;
                    ls += p;
                }
            ls += __shfl_xor(ls, 32);
            if (kh == 0) statf[256 + w * 64 + tj] = ls;
        }
        if (w == 0 && kh == 0) {
            statf[512 + l31]      = al[0];
            statf[512 + 32 + l31] = al[1];
        }
        // write P (bf16) to shB: layout [64 t][256 s] with XOR chunk swizzle
        #pragma unroll
        for (int i = 0; i < 2; i++)
            #pragma unroll
            for (int j = 0; j < 2; j++) {
                const int t = j * 32 + l31;
                #pragma unroll
                for (int g = 0; g < 4; g++) {
                    const int c = w * 8 + i * 4 + g;   // chunk of 8 s
                    u16 p4[4] = {f2bf(sacc[i][j][4*g]),   f2bf(sacc[i][j][4*g+1]),
                                 f2bf(sacc[i][j][4*g+2]), f2bf(sacc[i][j][4*g+3])};
                    *(uint2*)(shB + t * 256 + ((c ^ (t & 7)) * 8) + kh * 4) =
                        *(const uint2*)p4;
                }
            }
        __syncthreads();                                   // B2: psum/alpha/P visible
        #pragma unroll
        for (int j = 0; j < 2; j++) {
            const int tj = j * 32 + l31;
            float L = statf[256 + tj];
            #pragma unroll
            for (int wi = 1; wi < 4; wi++) L += statf[256 + wi * 64 + tj];
            l_run[j] = l_run[j] * al[j] + L;
        }
        // O rescale by alpha (quad reads at O's row mapping)
        #pragma unroll
        for (int i = 0; i < 2; i++)
            #pragma unroll
            for (int g = 0; g < 4; g++) {
                const int tq = i * 32 + 4 * kh + 8 * g;
                const float4 av = *(const float4*)(statf + 512 + tq);
                #pragma unroll
                for (int j = 0; j < 4; j++) {
                    oacc[i][j][4*g]   *= av.x;
                    oacc[i][j][4*g+1] *= av.y;
                    oacc[i][j][4*g+2] *= av.z;
                    oacc[i][j][4*g+3] *= av.w;
                }
            }
        __syncthreads();                                   // B3: alpha consumed
        // ---------------- phase 2: O += P . v^T (wave-local v) ----------------
        for (int sv = 0; sv < 256; sv += 32) {
            WAIT_ALL0();
            #pragma unroll
            for (int g = 0; g < 8; g++) {      // v rows: wave-private 128 c
                const int r = w * 128 + g * 16 + srow16;
                GLDS16(vb + (size_t)r * 1024 + s0 + sv +
                           ((sc4 ^ ((r >> 1) & 3)) * 8),
                       shA + r * 32 + sc4 * 8);
            }
            WAIT_VM0();
            #pragma unroll
            for (int ks = 0; ks < 2; ks++) {
                bf16x8 pf[2], vf[4];
                const int cbase = (sv >> 3) + ks * 2 + kh;
                #pragma unroll
                for (int i = 0; i < 2; i++) {
                    const int t = i * 32 + l31;
                    pf[i] = *(const bf16x8*)(shB + t * 256 +
                                             ((cbase ^ (t & 7)) * 8));
                }
                #pragma unroll
                for (int j = 0; j < 4; j++) {
                    const int cr = w * 128 + j * 32 + l31;
                    const int c4 = ks * 2 + kh;
                    vf[j] = *(const bf16x8*)(shA + cr * 32 +
                                             ((c4 ^ ((cr >> 1) & 3)) * 8));
                }
                #pragma unroll
                for (int i = 0; i < 2; i++)
                    #pragma unroll
                    for (int j = 0; j < 4; j++)
                        oacc[i][j] = __builtin_amdgcn_mfma_f32_32x32x16_bf16(
                            pf[i], vf[j], oacc[i][j], 0, 0, 0);
            }
        }
        __syncthreads();                                   // B4: P reads done
    }
    // ---------------- finalize: O /= l, store ----------------
    if (w == 0 && kh == 0) {
        statf[512 + l31]      = 1.0f / l_run[0];
        statf[512 + 32 + l31] = 1.0f / l_run[1];
    }
    __syncthreads();
    u16* ob = o + (size_t)b * 524288 + (size_t)t0 * 512;
    #pragma unroll
    for (int i = 0; i < 2; i++)
        #pragma unroll
        for (int g = 0; g < 4; g++) {
            const int tq = i * 32 + 4 * kh + 8 * g;
            const float4 lv = *(const float4*)(statf + 512 + tq);
            #pragma unroll
            for (int j = 0; j < 4; j++) {
                const int c = w * 128 + j * 32 + l31;
                u16* dst = ob + (size_t)tq * 512 + c;
                dst[0]    = f2bf(oacc[i][j][4*g]   * lv.x);
                dst[512]  = f2bf(oacc[i][j][4*g+1] * lv.y);
                dst[1024] = f2bf(oacc[i][j][4*g+2] * lv.z);
                dst[1536] = f2bf(oacc[i][j][4*g+3] * lv.w);
            }
        }
}

// ---------------------------------------------------------------------------
extern "C" void kernel_launch(void* const* d_in, const int* in_sizes, int n_in,
                              void* d_out, int out_size, void* d_ws, size_t ws_size,
                              hipStream_t stream)
{
    const float* x     = (const float*)d_in[0];
    const float* gamma = (const float*)d_in[1];
    const float* beta  = (const float*)d_in[2];
    const float* Wq    = (const float*)d_in[3];
    const float* bq    = (const float*)d_in[4];
    const float* Wk    = (const float*)d_in[5];
    const float* bk    = (const float*)d_in[6];
    const float* Wv    = (const float*)d_in[7];
    const float* bv    = (const float*)d_in[8];
    const float* Wp    = (const float*)d_in[9];
    const float* bp    = (const float*)d_in[10];

    char* ws = (char*)d_ws;
    u16*   Wqkv   = (u16*)(ws + 0);           //  1,572,864 B
    u16*   Wpb    = (u16*)(ws + 1572864);     //    524,288 B
    float* bqkv   = (float*)(ws + 2097152);   //      8,192 B
    u16*   ht     = (u16*)(ws + 2105344);     // 16,777,216 B (reused as h2)
    u16*   kt     = (u16*)(ws + 18882560);    // 16,777,216 B
    u16*   vv     = (u16*)(ws + 35659776);    // 16,777,216 B
    // total ws: 52,436,992 B
    u16*   qt  = (u16*)d_out;   // scratch: q [B,T,C] bf16 (16.8MB of 33.5MB)
    u16*   h2  = ht;
    float* out = (float*)d_out;

    convert_kernel<<<4096, 256, 0, stream>>>(Wq, Wk, Wv, Wp, bq, bk, bv,
                                             Wqkv, Wpb, bqkv);
    gn_kernel<<<dim3(32, 16), 256, 0, stream>>>(x, gamma, beta, ht);

    // GEMM1 qkv: M=1024(T) N=1536(3C) K=512 ; A=ht[B,T,C], B=Wqkv[3C,C]
    gemm_nt<0><<<dim3(12, 8, 16), 256, 0, stream>>>(
        ht, Wqkv, 524288, 0, 512, 512, 512,
        qt, kt, vv, nullptr, bqkv, nullptr);

    // Fused attention: scores+softmax+PV, q-tile 64, grid 16 t-tiles x 16 b
    attn_fused<<<dim3(16, 16), 256, 0, stream>>>(qt, kt, vv, h2);

    // GEMM4 proj+residual: M=1024(T) N=512 K=512 ; A=h2[B,T,C], B=Wp
    gemm_nt<3><<<dim3(4, 8, 16), 256, 0, stream>>>(
        h2, Wpb, 524288, 0, 512, 512, 512,
        nullptr, nullptr, nullptr, out, bp, x);
}

// Round 6
// 259.011 us; speedup vs baseline: 1.4069x; 1.4069x over previous
//
#include <hip/hip_runtime.h>

typedef unsigned short u16;
typedef __bf16 bf16x8 __attribute__((ext_vector_type(8)));
typedef float f32x16 __attribute__((ext_vector_type(16)));

__device__ __forceinline__ u16 f2bf(float f) {
    unsigned u = __builtin_bit_cast(unsigned, f);
    u += 0x7fffu + ((u >> 16) & 1u);
    return (u16)(u >> 16);
}

#define GLDS16(g, l) __builtin_amdgcn_global_load_lds( \
    (const __attribute__((address_space(1))) void*)(g), \
    (__attribute__((address_space(3))) void*)(l), 16, 0, 0)

// raw pipeline primitives (memory clobber pins GLDS/ds_read ordering)
#define BAR()       asm volatile("s_barrier" ::: "memory")
#define WAITVM(n)   asm volatile("s_waitcnt vmcnt(" #n ")" ::: "memory")

#define QK_SCALE 0.044194173824159216f

// ---------------------------------------------------------------------------
// Weight conversion: fp32 -> bf16 (Wq|Wk|Wv stacked, Wp), concat biases.
// Wq and bq pre-scaled by C^-1/2 so QK^T comes out pre-scaled.
// ---------------------------------------------------------------------------
__global__ __launch_bounds__(256) void convert_kernel(
    const float* __restrict__ Wq, const float* __restrict__ Wk,
    const float* __restrict__ Wv, const float* __restrict__ Wp,
    const float* __restrict__ bq, const float* __restrict__ bk,
    const float* __restrict__ bv,
    u16* __restrict__ Wqkv, u16* __restrict__ Wpb, float* __restrict__ bqkv)
{
    int idx = blockIdx.x * 256 + threadIdx.x;  // 4096 * 256 = 1048576
    if (idx < 786432) {
        int which = idx >> 18;
        int off   = idx & 262143;
        if (which == 0)
            Wqkv[idx] = f2bf(Wq[off] * QK_SCALE);
        else
            Wqkv[idx] = f2bf(((which == 1) ? Wk : Wv)[off]);
    } else {
        int off = idx - 786432;
        Wpb[off] = f2bf(Wp[off]);
    }
    if (idx < 1536) {
        float bvv = (idx < 512) ? bq[idx] * QK_SCALE
                  : (idx < 1024) ? bk[idx & 511] : bv[idx & 511];
        bqkv[idx] = bvv;
    }
}

// ---------------------------------------------------------------------------
// GroupNorm: x [B,C,T] fp32 -> h_t [B,T,C] bf16.  One block per (b, group).
// ---------------------------------------------------------------------------
__global__ __launch_bounds__(256) void gn_kernel(
    const float* __restrict__ x, const float* __restrict__ gamma,
    const float* __restrict__ beta, u16* __restrict__ ht)
{
    const int g = blockIdx.x, b = blockIdx.y, tid = threadIdx.x;
    const float* xg = x + ((size_t)b * 512 + (size_t)g * 16) * 1024;

    float s = 0.f, s2 = 0.f;
    const float4* x4 = (const float4*)xg;
    #pragma unroll 4
    for (int i = tid; i < 4096; i += 256) {
        float4 v = x4[i];
        s  += v.x + v.y + v.z + v.w;
        s2 += v.x * v.x + v.y * v.y + v.z * v.z + v.w * v.w;
    }
    #pragma unroll
    for (int off = 32; off; off >>= 1) {
        s  += __shfl_down(s, off);
        s2 += __shfl_down(s2, off);
    }
    __shared__ float rs[4], rs2[4];
    __shared__ float stat[2];
    const int w = tid >> 6;
    if ((tid & 63) == 0) { rs[w] = s; rs2[w] = s2; }
    __syncthreads();
    if (tid == 0) {
        float S  = rs[0] + rs[1] + rs[2] + rs[3];
        float S2 = rs2[0] + rs2[1] + rs2[2] + rs2[3];
        float mean = S * (1.f / 16384.f);
        float var  = S2 * (1.f / 16384.f) - mean * mean;
        stat[0] = mean;
        stat[1] = rsqrtf(var + 1e-5f);
    }
    __syncthreads();
    const float mean = stat[0], rstd = stat[1];

    float ga[16], be[16];
    #pragma unroll
    for (int ci = 0; ci < 16; ci++) {
        ga[ci] = gamma[g * 16 + ci];
        be[ci] = beta[g * 16 + ci];
    }
    for (int t = tid; t < 1024; t += 256) {
        u16 yv[16];
        #pragma unroll
        for (int ci = 0; ci < 16; ci++) {
            float v = xg[ci * 1024 + t];
            yv[ci] = f2bf((v - mean) * rstd * ga[ci] + be[ci]);
        }
        uint4* dst = (uint4*)(ht + ((size_t)b * 1024 + t) * 512 + g * 16);
        dst[0] = ((const uint4*)yv)[0];
        dst[1] = ((const uint4*)yv)[1];
    }
}

// ---------------------------------------------------------------------------
// Row softmax over bf16 scores [16384 rows, 1024 cols], in place.
// One wave per row, 16 elems per lane, butterfly reductions, no LDS.
// ---------------------------------------------------------------------------
__global__ __launch_bounds__(256) void softmax_kernel(u16* __restrict__ scores)
{
    const int row  = blockIdx.x * 4 + (threadIdx.x >> 6);
    const int lane = threadIdx.x & 63;
    u16* p = scores + (size_t)row * 1024 + lane * 16;

    uint4 w0 = ((const uint4*)p)[0];
    uint4 w1 = ((const uint4*)p)[1];
    unsigned wd[8] = {w0.x, w0.y, w0.z, w0.w, w1.x, w1.y, w1.z, w1.w};
    float v[16];
    #pragma unroll
    for (int i = 0; i < 8; i++) {
        v[2 * i]     = __builtin_bit_cast(float, wd[i] << 16);
        v[2 * i + 1] = __builtin_bit_cast(float, wd[i] & 0xffff0000u);
    }
    float m = v[0];
    #pragma unroll
    for (int i = 1; i < 16; i++) m = fmaxf(m, v[i]);
    #pragma unroll
    for (int off = 1; off < 64; off <<= 1) m = fmaxf(m, __shfl_xor(m, off));

    float s = 0.f;
    #pragma unroll
    for (int i = 0; i < 16; i++) { v[i] = __expf(v[i] - m); s += v[i]; }
    #pragma unroll
    for (int off = 1; off < 64; off <<= 1) s += __shfl_xor(s, off);
    const float inv = 1.0f / s;

    #pragma unroll
    for (int i = 0; i < 8; i++) {
        unsigned lo = f2bf(v[2 * i] * inv);
        unsigned hi = f2bf(v[2 * i + 1] * inv);
        wd[i] = lo | (hi << 16);
    }
    ((uint4*)p)[0] = make_uint4(wd[0], wd[1], wd[2], wd[3]);
    ((uint4*)p)[1] = make_uint4(wd[4], wd[5], wd[6], wd[7]);
}

// ---------------------------------------------------------------------------
// Pipelined NT GEMM: C[m][n] = sum_k A[m][k]*B[n][k], 128x128 tile, BK=64,
// double-buffered LDS (64 KB), raw s_barrier + vmcnt(8) so the next tile's
// global_load_lds stay in flight across the barrier (no full drain).
// 4 waves (2x2 of 64x64), each 2x2 frags of 32x32x16 MFMA.
// Dual-xor swizzle (R4-verified, 0 conflicts):
//   write: slot sc holds global chunk sc ^ key(r), key(r)=srow^((2s+(srow>>2))&7)
//   read:  chunk cidx at slot cidx ^ rkey, rkey=(l31&7)^((l31>>2)&7)
// MODE 0: qkv -> q,k bf16 row-major [B,T,C]; v bf16 [B,C,S]; +bias
// MODE 1: scores -> bf16 [B,T(n),S(m)]  (ushort4 along m)
// MODE 2: pv -> h2 bf16 [B,T(n),C(m)]   (ushort4 along m)
// MODE 3: proj -> fp32 d_out[B,C,T] = acc + bias[n] + x  (float4 along m)
// ---------------------------------------------------------------------------
template <int MODE>
__global__ __launch_bounds__(256) void gemm_nt(
    const u16* __restrict__ A, const u16* __restrict__ B,
    size_t strideA, size_t strideB, int lda, int ldb, int K,
    u16* __restrict__ o0, u16* __restrict__ o1, u16* __restrict__ o2,
    float* __restrict__ fo, const float* __restrict__ bias,
    const float* __restrict__ xres)
{
    __shared__ u16 As[2][8192];
    __shared__ u16 Bs[2][8192];

    const int tid   = threadIdx.x;
    const int lane  = tid & 63;
    const int wave  = tid >> 6;
    const int wm    = (wave >> 1) * 64;
    const int wn    = (wave & 1) * 64;
    const int l31   = lane & 31;
    const int khalf = lane >> 5;
    const int b     = blockIdx.z;

    const u16* Ab = A + (size_t)b * strideA + (size_t)blockIdx.y * 128 * lda;
    const u16* Bb = B + (size_t)b * strideB + (size_t)blockIdx.x * 128 * ldb;

    const int srow = lane >> 3;     // 0..7
    const int sc   = lane & 7;      // LDS chunk slot
    const int rkey = (l31 & 7) ^ ((l31 >> 2) & 7);

    f32x16 acc[2][2] = {};

    // prologue: fill buffer 0 (8 GLDS per wave)
    #pragma unroll
    for (int s = 0; s < 4; s++) {
        const int r   = wave * 32 + s * 8 + srow;
        const int key = srow ^ ((2 * s + (srow >> 2)) & 7);
        GLDS16(Ab + (size_t)r * lda + ((sc ^ key) * 8), As[0] + r * 64 + sc * 8);
        GLDS16(Bb + (size_t)r * ldb + ((sc ^ key) * 8), Bs[0] + r * 64 + sc * 8);
    }

    int cur = 0;
    for (int k0 = 0; k0 < K; k0 += 64) {
        if (k0 + 64 < K) {
            const int nb = cur ^ 1;
            const int kn = k0 + 64;
            #pragma unroll
            for (int s = 0; s < 4; s++) {
                const int r   = wave * 32 + s * 8 + srow;
                const int key = srow ^ ((2 * s + (srow >> 2)) & 7);
                GLDS16(Ab + (size_t)r * lda + kn + ((sc ^ key) * 8),
                       As[nb] + r * 64 + sc * 8);
                GLDS16(Bb + (size_t)r * ldb + kn + ((sc ^ key) * 8),
                       Bs[nb] + r * 64 + sc * 8);
            }
            WAITVM(8);      // drain only the 8 oldest (= current buffer fill)
        } else {
            WAITVM(0);
        }
        BAR();              // all waves' current buffer complete

        #pragma unroll
        for (int ks = 0; ks < 4; ks++) {
            const int slot = ((ks * 2 + khalf) ^ rkey) * 8;
            bf16x8 af[2], bfr[2];
            #pragma unroll
            for (int i = 0; i < 2; i++)
                af[i] = *(const bf16x8*)(As[cur] + (wm + i * 32 + l31) * 64 + slot);
            #pragma unroll
            for (int j = 0; j < 2; j++)
                bfr[j] = *(const bf16x8*)(Bs[cur] + (wn + j * 32 + l31) * 64 + slot);
            #pragma unroll
            for (int i = 0; i < 2; i++)
                #pragma unroll
                for (int j = 0; j < 2; j++)
                    acc[i][j] = __builtin_amdgcn_mfma_f32_32x32x16_bf16(
                        af[i], bfr[j], acc[i][j], 0, 0, 0);
        }
        BAR();              // all waves done reading before this buffer refills
        cur ^= 1;
    }

    // Epilogue. C/D: col = lane&31, row = (reg&3) + 8*(reg>>2) + 4*(lane>>5)
    const int m_base = blockIdx.y * 128 + wm + 4 * khalf;
    const int n_base = blockIdx.x * 128 + wn + l31;

    #pragma unroll
    for (int i = 0; i < 2; i++) {
        #pragma unroll
        for (int j = 0; j < 2; j++) {
            const int n = n_base + j * 32;
            float bv = 0.f;
            if (MODE == 0 || MODE == 3) bv = bias[n];
            #pragma unroll
            for (int g = 0; g < 4; g++) {
                const int m = m_base + i * 32 + 8 * g;
                const float a0 = acc[i][j][4 * g]     + bv;
                const float a1 = acc[i][j][4 * g + 1] + bv;
                const float a2 = acc[i][j][4 * g + 2] + bv;
                const float a3 = acc[i][j][4 * g + 3] + bv;
                if (MODE == 0) {
                    if (n < 1024) {          // q or k: row-major [.,C], scalar
                        u16* dst = (n < 512) ? o0 : o1;
                        const int nn = n & 511;
                        dst[((size_t)b * 1024 + m) * 512 + nn]     = f2bf(a0);
                        dst[((size_t)b * 1024 + m + 1) * 512 + nn] = f2bf(a1);
                        dst[((size_t)b * 1024 + m + 2) * 512 + nn] = f2bf(a2);
                        dst[((size_t)b * 1024 + m + 3) * 512 + nn] = f2bf(a3);
                    } else {                 // v: [B,C,S], ushort4
                        ushort4 hv = {f2bf(a0), f2bf(a1), f2bf(a2), f2bf(a3)};
                        *(ushort4*)(o2 + ((size_t)b * 512 + (n - 1024)) * 1024 + m) = hv;
                    }
                } else if (MODE == 1) {      // scores[b][t=n][s=m] bf16
                    ushort4 hv = {f2bf(a0), f2bf(a1), f2bf(a2), f2bf(a3)};
                    *(ushort4*)(o0 + ((size_t)b * 1024 + n) * 1024 + m) = hv;
                } else if (MODE == 2) {      // h2[b][t=n][c=m] bf16
                    ushort4 hv = {f2bf(a0), f2bf(a1), f2bf(a2), f2bf(a3)};
                    *(ushort4*)(o0 + ((size_t)b * 1024 + n) * 512 + m) = hv;
                } else {                     // proj + bias + residual, [B,C,T]
                    const size_t off = ((size_t)b * 512 + n) * 1024 + m;
                    const float4 xv = *(const float4*)(xres + off);
                    float4 ov = {a0 + xv.x, a1 + xv.y, a2 + xv.z, a3 + xv.w};
                    *(float4*)(fo + off) = ov;
                }
            }
        }
    }
}

// ---------------------------------------------------------------------------
extern "C" void kernel_launch(void* const* d_in, const int* in_sizes, int n_in,
                              void* d_out, int out_size, void* d_ws, size_t ws_size,
                              hipStream_t stream)
{
    const float* x     = (const float*)d_in[0];
    const float* gamma = (const float*)d_in[1];
    const float* beta  = (const float*)d_in[2];
    const float* Wq    = (const float*)d_in[3];
    const float* bq    = (const float*)d_in[4];
    const float* Wk    = (const float*)d_in[5];
    const float* bk    = (const float*)d_in[6];
    const float* Wv    = (const float*)d_in[7];
    const float* bv    = (const float*)d_in[8];
    const float* Wp    = (const float*)d_in[9];
    const float* bp    = (const float*)d_in[10];

    char* ws = (char*)d_ws;
    u16*   Wqkv   = (u16*)(ws + 0);           //  1,572,864 B
    u16*   Wpb    = (u16*)(ws + 1572864);     //    524,288 B
    float* bqkv   = (float*)(ws + 2097152);   //      8,192 B
    u16*   ht     = (u16*)(ws + 2105344);     // 16,777,216 B (reused as h2)
    u16*   kt     = (u16*)(ws + 18882560);    // 16,777,216 B
    u16*   vv     = (u16*)(ws + 35659776);    // 16,777,216 B
    u16*   scores = (u16*)(ws + 52436992);    // 33,554,432 B bf16
    // total ws: 85,991,424 B
    u16*   qt  = (u16*)d_out;   // scratch: q [B,T,C] bf16 (16.8MB of 33.5MB)
    u16*   h2  = ht;
    float* out = (float*)d_out;

    convert_kernel<<<4096, 256, 0, stream>>>(Wq, Wk, Wv, Wp, bq, bk, bv,
                                             Wqkv, Wpb, bqkv);
    gn_kernel<<<dim3(32, 16), 256, 0, stream>>>(x, gamma, beta, ht);

    // GEMM1 qkv: M=1024(T) N=1536(3C) K=512 ; A=ht[B,T,C], B=Wqkv[3C,C]
    gemm_nt<0><<<dim3(12, 8, 16), 256, 0, stream>>>(
        ht, Wqkv, 524288, 0, 512, 512, 512,
        qt, kt, vv, nullptr, bqkv, nullptr);

    // GEMM2 scores: M=1024(S) N=1024(T) K=512 ; A=kt, B=qt (scale pre-folded)
    gemm_nt<1><<<dim3(8, 8, 16), 256, 0, stream>>>(
        kt, qt, 524288, 524288, 512, 512, 512,
        scores, nullptr, nullptr, nullptr, nullptr, nullptr);

    softmax_kernel<<<4096, 256, 0, stream>>>(scores);

    // GEMM3 pv: M=512(C) N=1024(T) K=1024 ; A=v[C,S], B=P[T,S] compact bf16
    gemm_nt<2><<<dim3(8, 4, 16), 256, 0, stream>>>(
        vv, scores, 524288, 1048576, 1024, 1024, 1024,
        h2, nullptr, nullptr, nullptr, nullptr, nullptr);

    // GEMM4 proj+residual: M=1024(T) N=512 K=512 ; A=h2[B,T,C], B=Wp
    gemm_nt<3><<<dim3(4, 8, 16), 256, 0, stream>>>(
        h2, Wpb, 524288, 0, 512, 512, 512,
        nullptr, nullptr, nullptr, out, bp, x);
}